// Round 2
// baseline (138.706 us; speedup 1.0000x reference)
//
#include <hip/hip_runtime.h>

#define S_DIM 16
#define B_DIM 512
#define H_DIM 2048
#define EPS 1e-8f

typedef short bf16x8 __attribute__((ext_vector_type(8)));
typedef float f32x4 __attribute__((ext_vector_type(4)));

__device__ __forceinline__ unsigned short f2bf(float f) {
    union { float f; unsigned int u; } v; v.f = f;
    unsigned int u = v.u;
    unsigned int r = (u + 0x7fffu + ((u >> 16) & 1u)) >> 16;
    return (unsigned short)r;
}

__device__ __forceinline__ float dot4(const float4& a, const float4& b) {
    return a.x*b.x + a.y*b.y + a.z*b.z + a.w*b.w;
}

// ---------------- Kernel 1: sims + weighted mean -> wRep (bf16) ----------------
// grid: B_DIM blocks x 1024 threads (16 waves). Wave w owns s = w.
// Each lane holds 8 float4 of its row (h = 4*(i*64+lane)). E read exactly once.
// Live regs per lane: og[8] (32) + e[8] (32) + temps -> ~100, fits 128 @ 16 waves/CU.
__global__ __launch_bounds__(1024) void simwrep_kernel(
    const float* __restrict__ OG, const float* __restrict__ E,
    unsigned short* __restrict__ wrep) {
    const int b = blockIdx.x;
    const int t = threadIdx.x;
    const int lane = t & 63;
    const int wave = t >> 6;          // 0..15 == s

    __shared__ float4 buf[16][512];   // 128 KiB

    // OG row + ||og||^2 (per-wave redundant; L1-hot after first wave)
    const float4* og4 = (const float4*)(OG + (size_t)b * H_DIM);
    float4 og[8];
    float og2 = 0.f;
    #pragma unroll
    for (int i = 0; i < 8; ++i) {
        og[i] = og4[i * 64 + lane];
        og2 += dot4(og[i], og[i]);
    }
    #pragma unroll
    for (int m = 32; m >= 1; m >>= 1) og2 += __shfl_xor(og2, m, 64);
    const float onorm = sqrtf(og2);

    const float4* e4 = (const float4*)(E + ((size_t)wave * B_DIM + b) * H_DIM);
    float4 e[8];
    float d = 0.f, n = 0.f;
    #pragma unroll
    for (int i = 0; i < 8; ++i) {
        e[i] = e4[i * 64 + lane];
        d += dot4(e[i], og[i]);
        n += dot4(e[i], e[i]);
    }
    #pragma unroll
    for (int m = 32; m >= 1; m >>= 1) {
        d += __shfl_xor(d, m, 64);
        n += __shfl_xor(n, m, 64);
    }
    const float sim = d / fmaxf(sqrtf(n) * onorm, EPS);

    #pragma unroll
    for (int i = 0; i < 8; ++i) {
        float4 p;
        p.x = e[i].x * sim; p.y = e[i].y * sim;
        p.z = e[i].z * sim; p.w = e[i].w * sim;
        buf[wave][i * 64 + lane] = p;
    }
    __syncthreads();

    // threads 0..511: sum the 16 wave partials for float4-chunk t, mean, bf16
    if (t < 512) {
        float4 s = buf[0][t];
        #pragma unroll
        for (int w = 1; w < 16; ++w) {
            float4 v = buf[w][t];
            s.x += v.x; s.y += v.y; s.z += v.z; s.w += v.w;
        }
        const float sc = 1.f / (float)S_DIM;
        ushort4 o;
        o.x = f2bf(s.x * sc); o.y = f2bf(s.y * sc);
        o.z = f2bf(s.z * sc); o.w = f2bf(s.w * sc);
        ((ushort4*)wrep)[(size_t)b * (H_DIM / 4) + t] = o;
    }
}

// ---------------- Kernel 2: split-K GEMM partial = wRep @ W^T ----------------
// A: 512x2048 bf16 K-contig. W: 2048x2048 fp32 (row n = out col n, K-contig),
// converted to bf16 on the fly during LDS staging.
// 64x64 tile, BK=32, 4 waves each 32x32 (2x2 of 16x16x32). blockIdx.z = K-half.
__global__ __launch_bounds__(256) void gemm_splitk_kernel(
    const unsigned short* __restrict__ A, const float* __restrict__ W,
    float* __restrict__ partial) {
    const int n0 = blockIdx.x * 64;
    const int m0 = blockIdx.y * 64;
    const int kz = blockIdx.z;               // 0 or 1
    const int kbase = kz * (H_DIM / 2);      // 1024

    __shared__ unsigned short As[64][40];    // +8 pad
    __shared__ unsigned short Ws[64][40];

    const int t = threadIdx.x;
    const int lane = t & 63;
    const int wave = t >> 6;
    const int wm = (wave & 1) * 32;
    const int wn = (wave >> 1) * 32;
    const int lr = t >> 2;                   // staging row 0..63
    const int lq = t & 3;                    // staging k-quad (8 elems each)

    const size_t aoff = (size_t)(m0 + lr) * H_DIM + kbase + lq * 8;
    const float* wp = W + (size_t)(n0 + lr) * H_DIM + kbase + lq * 8;

    f32x4 acc00 = {0.f, 0.f, 0.f, 0.f};
    f32x4 acc01 = {0.f, 0.f, 0.f, 0.f};
    f32x4 acc10 = {0.f, 0.f, 0.f, 0.f};
    f32x4 acc11 = {0.f, 0.f, 0.f, 0.f};

    const int row = lane & 15;
    const int q = lane >> 4;

    uint4 av = *(const uint4*)(A + aoff);
    float4 wv0 = *(const float4*)(wp);
    float4 wv1 = *(const float4*)(wp + 4);

    for (int k0 = 0; k0 < H_DIM / 2; k0 += 32) {
        *(uint4*)&As[lr][lq * 8] = av;
        ushort4 wlo, whi;
        wlo.x = f2bf(wv0.x); wlo.y = f2bf(wv0.y); wlo.z = f2bf(wv0.z); wlo.w = f2bf(wv0.w);
        whi.x = f2bf(wv1.x); whi.y = f2bf(wv1.y); whi.z = f2bf(wv1.z); whi.w = f2bf(wv1.w);
        *(ushort4*)&Ws[lr][lq * 8] = wlo;
        *(ushort4*)&Ws[lr][lq * 8 + 4] = whi;
        __syncthreads();
        if (k0 + 32 < H_DIM / 2) {           // register prefetch of next tiles
            av = *(const uint4*)(A + aoff + k0 + 32);
            wv0 = *(const float4*)(wp + k0 + 32);
            wv1 = *(const float4*)(wp + k0 + 36);
        }
        bf16x8 a0 = *(const bf16x8*)&As[wm + row][q * 8];
        bf16x8 a1 = *(const bf16x8*)&As[wm + 16 + row][q * 8];
        bf16x8 b0 = *(const bf16x8*)&Ws[wn + row][q * 8];
        bf16x8 b1 = *(const bf16x8*)&Ws[wn + 16 + row][q * 8];
        acc00 = __builtin_amdgcn_mfma_f32_16x16x32_bf16(a0, b0, acc00, 0, 0, 0);
        acc01 = __builtin_amdgcn_mfma_f32_16x16x32_bf16(a0, b1, acc01, 0, 0, 0);
        acc10 = __builtin_amdgcn_mfma_f32_16x16x32_bf16(a1, b0, acc10, 0, 0, 0);
        acc11 = __builtin_amdgcn_mfma_f32_16x16x32_bf16(a1, b1, acc11, 0, 0, 0);
        __syncthreads();
    }

    // D mapping: col=lane&15, row=(lane>>4)*4+reg
    float* pz = partial + (size_t)kz * B_DIM * H_DIM;
    const int col = lane & 15;
    #pragma unroll
    for (int r = 0; r < 4; ++r) {
        const int mr = q * 4 + r;
        float* o0 = pz + (size_t)(m0 + wm + mr) * H_DIM + n0 + wn;
        float* o1 = pz + (size_t)(m0 + wm + 16 + mr) * H_DIM + n0 + wn;
        o0[col]      = acc00[r];
        o0[16 + col] = acc01[r];
        o1[col]      = acc10[r];
        o1[16 + col] = acc11[r];
    }
}

// ---------------- Kernel 3: out = p0 + p1 + bias ----------------
__global__ __launch_bounds__(256) void reduce_kernel(
    const float* __restrict__ partial, const float* __restrict__ bias,
    float* __restrict__ out) {
    const int i = blockIdx.x * 256 + threadIdx.x;     // float4 index
    const float4 a = ((const float4*)partial)[i];
    const float4 c = ((const float4*)partial)[i + B_DIM * H_DIM / 4];
    const float4 bs = ((const float4*)bias)[i & (H_DIM / 4 - 1)];
    float4 o;
    o.x = a.x + c.x + bs.x; o.y = a.y + c.y + bs.y;
    o.z = a.z + c.z + bs.z; o.w = a.w + c.w + bs.w;
    ((float4*)out)[i] = o;
}

extern "C" void kernel_launch(void* const* d_in, const int* in_sizes, int n_in,
                              void* d_out, int out_size, void* d_ws, size_t ws_size,
                              hipStream_t stream) {
    const float* OG   = (const float*)d_in[0];
    const float* E    = (const float*)d_in[1];
    const float* W    = (const float*)d_in[2];
    const float* bias = (const float*)d_in[3];
    float* out = (float*)d_out;

    unsigned short* wrep = (unsigned short*)d_ws;                     // 512*2048 bf16 = 2 MiB
    float* partial = (float*)((char*)d_ws + (size_t)B_DIM * H_DIM * 2); // 2*512*2048 fp32 = 8 MiB

    simwrep_kernel<<<B_DIM, 1024, 0, stream>>>(OG, E, wrep);
    gemm_splitk_kernel<<<dim3(H_DIM / 64, B_DIM / 64, 2), 256, 0, stream>>>(wrep, W, partial);
    reduce_kernel<<<(B_DIM * H_DIM / 4) / 256, 256, 0, stream>>>(partial, bias, out);
}